// Round 9
// baseline (303.470 us; speedup 1.0000x reference)
//
#include <hip/hip_runtime.h>
#include <hip/hip_bf16.h>

#define FEAT 64

// RNE pack of two fp32 into one u32 of 2 bf16 (lo, hi)
__device__ inline uint packbf2(float lo, float hi) {
    uint ul = __float_as_uint(lo), uh = __float_as_uint(hi);
    ul += 0x7FFFu + ((ul >> 16) & 1u);
    uh += 0x7FFFu + ((uh >> 16) & 1u);
    return (ul >> 16) | (uh & 0xFFFF0000u);
}

// unpack uint4 (8 bf16) -> two float4
__device__ inline void unpack8(uint4 q, float4& va, float4& vb) {
    va.x = __uint_as_float(q.x << 16);
    va.y = __uint_as_float(q.x & 0xFFFF0000u);
    va.z = __uint_as_float(q.y << 16);
    va.w = __uint_as_float(q.y & 0xFFFF0000u);
    vb.x = __uint_as_float(q.z << 16);
    vb.y = __uint_as_float(q.z & 0xFFFF0000u);
    vb.z = __uint_as_float(q.w << 16);
    vb.w = __uint_as_float(q.w & 0xFFFF0000u);
}

// ---------------------------------------------------------------------------
// Kernel 1 (merged prep): blocks [0,normBlocks): inverse norms rn, raw norms
// nrm, and the NORMALIZED bf16 mirror xhn = bf16(x * rn) (feature-permuted:
// lane sub holds feats [4s,4s+4) and [32+4s,..) in one uint4).  Remaining
// blocks: row_ptr build from the SORTED row_index.  Block 0 also zeroes the
// 128 histogram/fill counters used by the degree sort.
// ---------------------------------------------------------------------------
__global__ void prep_kernel(const float* __restrict__ x,
                            float* __restrict__ rn,
                            float* __restrict__ nrm,
                            uint4* __restrict__ xhn,
                            const int* __restrict__ row,
                            int* __restrict__ row_ptr,
                            int* __restrict__ hist,
                            int N, int E, int normBlocks) {
    if (blockIdx.x == 0 && threadIdx.x < 128) hist[threadIdx.x] = 0;
    if ((int)blockIdx.x < normBlocks) {
        int wid  = blockIdx.x * (blockDim.x >> 6) + (threadIdx.x >> 6);
        int lane = threadIdx.x & 63;
        int g    = lane >> 3;
        int sub  = lane & 7;
        int r    = wid * 8 + g;
        if (r >= N) return;
        const char* xB = (const char*)x;
        uint roff = ((uint)r << 8) + ((uint)sub << 4);
        float4 xa = *reinterpret_cast<const float4*>(xB + roff);
        float4 xb = *reinterpret_cast<const float4*>(xB + roff + 128);
        float q = xa.x*xa.x + xa.y*xa.y + xa.z*xa.z + xa.w*xa.w
                + xb.x*xb.x + xb.y*xb.y + xb.z*xb.z + xb.w*xb.w;
        q += __shfl_xor(q, 1);
        q += __shfl_xor(q, 2);
        q += __shfl_xor(q, 4);
        float qe  = q + 1e-8f;
        float rnr = rsqrtf(qe);
        if (sub == 0) { rn[r] = rnr; nrm[r] = qe * rnr; }   // nrm = sqrt(qe)
        uint4 p;
        p.x = packbf2(xa.x * rnr, xa.y * rnr);
        p.y = packbf2(xa.z * rnr, xa.w * rnr);
        p.z = packbf2(xb.x * rnr, xb.y * rnr);
        p.w = packbf2(xb.z * rnr, xb.w * rnr);
        xhn[r * 8 + sub] = p;
    } else {
        int e = (blockIdx.x - normBlocks) * blockDim.x + threadIdx.x;
        if (e >= E) return;
        int curr = row[e];
        if (e == 0) {
            for (int r = 0; r <= curr; ++r) row_ptr[r] = 0;
        } else {
            int prev = row[e - 1];
            for (int r = prev + 1; r <= curr; ++r) row_ptr[r] = e;
        }
        if (e == E - 1) {
            for (int r = curr + 1; r <= N; ++r) row_ptr[r] = E;
        }
    }
}

// ---------------------------------------------------------------------------
// Degree-sort kernels.  Row placement uses int atomics (non-deterministic
// order WITHIN a same-degree bucket), but each row's arithmetic and output
// slot are fixed -> d_out is bit-deterministic regardless of placement.
// ---------------------------------------------------------------------------
__global__ void deghist_kernel(const int* __restrict__ row_ptr,
                               int* __restrict__ hist, int N) {
    int r = blockIdx.x * blockDim.x + threadIdx.x;
    if (r >= N) return;
    int d = min(row_ptr[r + 1] - row_ptr[r], 63);
    atomicAdd(&hist[d], 1);
}

__global__ void scan_kernel(const int* __restrict__ hist,
                            int* __restrict__ bbase) {   // <<<1,64>>>
    int lane = threadIdx.x;
    int v = hist[lane];
    int inc = v;
    #pragma unroll
    for (int off = 1; off < 64; off <<= 1) {
        int t = __shfl_up(inc, off);
        if (lane >= off) inc += t;
    }
    bbase[lane] = inc - v;    // exclusive prefix
}

__global__ void scatter_kernel(const int* __restrict__ row_ptr,
                               const int* __restrict__ bbase,
                               int* __restrict__ fill,
                               int* __restrict__ row_order, int N) {
    int r = blockIdx.x * blockDim.x + threadIdx.x;
    if (r >= N) return;
    int d = min(row_ptr[r + 1] - row_ptr[r], 63);
    int pos = bbase[d] + atomicAdd(&fill[d], 1);
    row_order[pos] = r;
}

// ---------------------------------------------------------------------------
// Kernel 5: FUSED attention + shift-free softmax + aggregation.
// One 8-lane group per DEGREE-SORTED row (equal trip counts within a wave),
// 8 rows per wave.  xhn is pre-normalized, x_r is pre-scaled by beta*rn_r,
// so att = dot() directly: no per-edge rn shfl/mul.  col + nrm are
// group-uniform scalar loads (broadcast), 3-stage pipelined:
//   stage A: cols for quad k+2;  stage B: gathers+norms for quad k+1 (cols
//   loaded last iter);  stage C: process quad k.
// Per edge: 1 gather, 1/1 uniform col/nrm load, 8 unpack, 8 FMA dot,
// 3 shfl reduce, 1 exp, 1 mul, 8 FMA accumulate.
// ---------------------------------------------------------------------------
__global__ void fused_kernel(const float* __restrict__ x,
                             const uint4* __restrict__ xhn,
                             const float* __restrict__ rn,
                             const float* __restrict__ nrm,
                             const float* __restrict__ beta,
                             const int* __restrict__ row_ptr,
                             const int* __restrict__ col,
                             const int* __restrict__ row_order,
                             float* __restrict__ out, int N, int E) {
    int wid  = blockIdx.x * (blockDim.x >> 6) + (threadIdx.x >> 6);
    int lane = threadIdx.x & 63;
    int g    = lane >> 3;
    int sub  = lane & 7;
    int slot = wid * 8 + g;
    bool rv  = (slot < N);

    int r = 0;
    if (rv) r = row_order[slot];
    int start = 0, deg = 0;
    if (rv) {
        start = row_ptr[r];
        deg   = row_ptr[r + 1] - start;
    }

    // x_r scaled by beta*rn_r:  att = dot(xr_scaled, xhn_c)
    float4 xa = make_float4(0.f, 0.f, 0.f, 0.f);
    float4 xb = make_float4(0.f, 0.f, 0.f, 0.f);
    if (rv) {
        const char* xB = (const char*)x;
        uint roff = ((uint)r << 8) + ((uint)sub << 4);
        xa = *reinterpret_cast<const float4*>(xB + roff);
        xb = *reinterpret_cast<const float4*>(xB + roff + 128);
        float brn = beta[0] * rn[r];
        xa.x *= brn; xa.y *= brn; xa.z *= brn; xa.w *= brn;
        xb.x *= brn; xb.y *= brn; xb.z *= brn; xb.w *= brn;
    }

    int Em1 = E - 1;
    // prologue: cols of quad 0 and quad 1 (uniform per group), gathers+norms
    // of quad 0.  Clamped indices stay in-bounds; tails masked at e_j.
    int c0 = col[min(start + 0, Em1)], c1 = col[min(start + 1, Em1)];
    int c2 = col[min(start + 2, Em1)], c3 = col[min(start + 3, Em1)];
    int nc0 = col[min(start + 4, Em1)], nc1 = col[min(start + 5, Em1)];
    int nc2 = col[min(start + 6, Em1)], nc3 = col[min(start + 7, Em1)];
    uint4 q0 = xhn[c0 * 8 + sub], q1 = xhn[c1 * 8 + sub];
    uint4 q2 = xhn[c2 * 8 + sub], q3 = xhn[c3 * 8 + sub];
    float n0 = nrm[c0], n1 = nrm[c1], n2 = nrm[c2], n3 = nrm[c3];

    float  s  = 0.f;
    float4 aa = make_float4(0.f, 0.f, 0.f, 0.f);
    float4 ab = make_float4(0.f, 0.f, 0.f, 0.f);

    for (int base = 0; base < deg; base += 4) {
        // stage A: cols for quad base+8
        int b2 = start + base + 8;
        int t0 = col[min(b2 + 0, Em1)], t1 = col[min(b2 + 1, Em1)];
        int t2 = col[min(b2 + 2, Em1)], t3 = col[min(b2 + 3, Em1)];
        // stage B: gathers + norms for quad base+4 (cols loaded last iter)
        uint4 nq0 = xhn[nc0 * 8 + sub], nq1 = xhn[nc1 * 8 + sub];
        uint4 nq2 = xhn[nc2 * 8 + sub], nq3 = xhn[nc3 * 8 + sub];
        float nn0 = nrm[nc0], nn1 = nrm[nc1];
        float nn2 = nrm[nc2], nn3 = nrm[nc3];

        // stage C: process current quad
        float4 va0, vb0, va1, vb1, va2, vb2, va3, vb3;
        unpack8(q0, va0, vb0);  unpack8(q1, va1, vb1);
        unpack8(q2, va2, vb2);  unpack8(q3, va3, vb3);

        float d0 = xa.x*va0.x + xa.y*va0.y + xa.z*va0.z + xa.w*va0.w
                 + xb.x*vb0.x + xb.y*vb0.y + xb.z*vb0.z + xb.w*vb0.w;
        float d1 = xa.x*va1.x + xa.y*va1.y + xa.z*va1.z + xa.w*va1.w
                 + xb.x*vb1.x + xb.y*vb1.y + xb.z*vb1.z + xb.w*vb1.w;
        float d2 = xa.x*va2.x + xa.y*va2.y + xa.z*va2.z + xa.w*va2.w
                 + xb.x*vb2.x + xb.y*vb2.y + xb.z*vb2.z + xb.w*vb2.w;
        float d3 = xa.x*va3.x + xa.y*va3.y + xa.z*va3.z + xa.w*va3.w
                 + xb.x*vb3.x + xb.y*vb3.y + xb.z*vb3.z + xb.w*vb3.w;
        d0 += __shfl_xor(d0, 1);  d1 += __shfl_xor(d1, 1);
        d2 += __shfl_xor(d2, 1);  d3 += __shfl_xor(d3, 1);
        d0 += __shfl_xor(d0, 2);  d1 += __shfl_xor(d1, 2);
        d2 += __shfl_xor(d2, 2);  d3 += __shfl_xor(d3, 2);
        d0 += __shfl_xor(d0, 4);  d1 += __shfl_xor(d1, 4);
        d2 += __shfl_xor(d2, 4);  d3 += __shfl_xor(d3, 4);

        float e0 = (base + 0 < deg) ? __expf(d0) : 0.f;   // att bounded by |beta|
        float e1 = (base + 1 < deg) ? __expf(d1) : 0.f;
        float e2 = (base + 2 < deg) ? __expf(d2) : 0.f;
        float e3 = (base + 3 < deg) ? __expf(d3) : 0.f;
        s += (e0 + e1) + (e2 + e3);

        float w0 = e0 * n0, w1 = e1 * n1, w2 = e2 * n2, w3 = e3 * n3;
        aa.x += w0*va0.x + w1*va1.x + w2*va2.x + w3*va3.x;
        aa.y += w0*va0.y + w1*va1.y + w2*va2.y + w3*va3.y;
        aa.z += w0*va0.z + w1*va1.z + w2*va2.z + w3*va3.z;
        aa.w += w0*va0.w + w1*va1.w + w2*va2.w + w3*va3.w;
        ab.x += w0*vb0.x + w1*vb1.x + w2*vb2.x + w3*vb3.x;
        ab.y += w0*vb0.y + w1*vb1.y + w2*vb2.y + w3*vb3.y;
        ab.z += w0*vb0.z + w1*vb1.z + w2*vb2.z + w3*vb3.z;
        ab.w += w0*vb0.w + w1*vb1.w + w2*vb2.w + w3*vb3.w;

        // rotate pipeline
        q0 = nq0; q1 = nq1; q2 = nq2; q3 = nq3;
        n0 = nn0; n1 = nn1; n2 = nn2; n3 = nn3;
        nc0 = t0; nc1 = t1; nc2 = t2; nc3 = t3;
    }

    float inv = 1.0f / fmaxf(s, 1e-16f);      // deg==0 -> out = 0
    if (rv) {
        uint roff = ((uint)r << 8) + ((uint)sub << 4);
        *reinterpret_cast<float4*>((char*)out + roff) =
            make_float4(aa.x * inv, aa.y * inv, aa.z * inv, aa.w * inv);
        *reinterpret_cast<float4*>((char*)out + roff + 128) =
            make_float4(ab.x * inv, ab.y * inv, ab.z * inv, ab.w * inv);
    }
}

// ---------------------------------------------------------------------------
extern "C" void kernel_launch(void* const* d_in, const int* in_sizes, int n_in,
                              void* d_out, int out_size, void* d_ws, size_t ws_size,
                              hipStream_t stream) {
    const float* x    = (const float*)d_in[0];
    const float* beta = (const float*)d_in[1];
    const int*   row  = (const int*)d_in[2];
    const int*   col  = (const int*)d_in[3];
    float*       out  = (float*)d_out;

    const int N = in_sizes[0] / FEAT;   // 50000
    const int E = in_sizes[2];          // 800000

    // Workspace layout (512B-aligned chunks):
    // rn[N] | nrm[N] | row_ptr[N+1] | hist[64]+fill[64]+bbase[64] |
    // row_order[N] | xhn[N*8 uint4]
    char*  ws = (char*)d_ws;
    size_t o  = 0;
    auto alloc = [&](size_t bytes) {
        size_t cur = o;
        o = (o + bytes + 511) & ~(size_t)511;
        return cur;
    };
    float* rn        = (float*)(ws + alloc((size_t)N * 4));
    float* nrm       = (float*)(ws + alloc((size_t)N * 4));
    int*   row_ptr   = (int*)  (ws + alloc((size_t)(N + 1) * 4));
    int*   hist      = (int*)  (ws + alloc(192 * 4));
    int*   fill      = hist + 64;
    int*   bbase     = hist + 128;
    int*   row_order = (int*)  (ws + alloc((size_t)N * 4));
    uint4* xhn       = (uint4*)(ws + alloc((size_t)N * 128));

    {   // prep: norms + normalized bf16 mirror + rowptr + counter zeroing
        int normBlocks = (N + 31) / 32;
        int edgeBlocks = (E + 255) / 256;
        prep_kernel<<<normBlocks + edgeBlocks, 256, 0, stream>>>(
            x, rn, nrm, xhn, row, row_ptr, hist, N, E, normBlocks);
    }
    {   // degree counting-sort: histogram -> 64-bin scan -> scatter
        int grid = (N + 255) / 256;
        deghist_kernel<<<grid, 256, 0, stream>>>(row_ptr, hist, N);
        scan_kernel<<<1, 64, 0, stream>>>(hist, bbase);
        scatter_kernel<<<grid, 256, 0, stream>>>(row_ptr, bbase, fill,
                                                 row_order, N);
    }
    {   // fused: 8 degree-sorted rows per wave, 4 waves per block
        int waves = (N + 7) / 8;
        int grid  = (waves + 3) / 4;
        fused_kernel<<<grid, 256, 0, stream>>>(
            x, xhn, rn, nrm, beta, row_ptr, col, row_order, out, N, E);
    }
}

// Round 10
// 86.426 us; speedup vs baseline: 3.5113x; 3.5113x over previous
//
#include <hip/hip_runtime.h>
#include <hip/hip_bf16.h>

#define FEAT 64

// RNE pack of two fp32 into one u32 of 2 bf16 (lo, hi)
__device__ inline uint packbf2(float lo, float hi) {
    uint ul = __float_as_uint(lo), uh = __float_as_uint(hi);
    ul += 0x7FFFu + ((ul >> 16) & 1u);
    uh += 0x7FFFu + ((uh >> 16) & 1u);
    return (ul >> 16) | (uh & 0xFFFF0000u);
}

// unpack uint4 (8 bf16) -> two float4
__device__ inline void unpack8(uint4 q, float4& va, float4& vb) {
    va.x = __uint_as_float(q.x << 16);
    va.y = __uint_as_float(q.x & 0xFFFF0000u);
    va.z = __uint_as_float(q.y << 16);
    va.w = __uint_as_float(q.y & 0xFFFF0000u);
    vb.x = __uint_as_float(q.z << 16);
    vb.y = __uint_as_float(q.z & 0xFFFF0000u);
    vb.z = __uint_as_float(q.w << 16);
    vb.w = __uint_as_float(q.w & 0xFFFF0000u);
}

// ---------------------------------------------------------------------------
// Kernel 1 (merged prep): blocks [0,normBlocks): inverse norms rn, raw norms
// nrm, and the NORMALIZED bf16 mirror xhn = bf16(x * rn).  Remaining blocks:
// row_ptr build from the SORTED row_index.
// ---------------------------------------------------------------------------
__global__ void prep_kernel(const float* __restrict__ x,
                            float* __restrict__ rn,
                            float* __restrict__ nrm,
                            uint4* __restrict__ xhn,
                            const int* __restrict__ row,
                            int* __restrict__ row_ptr,
                            int N, int E, int normBlocks) {
    if ((int)blockIdx.x < normBlocks) {
        int wid  = blockIdx.x * (blockDim.x >> 6) + (threadIdx.x >> 6);
        int lane = threadIdx.x & 63;
        int g    = lane >> 3;
        int sub  = lane & 7;
        int r    = wid * 8 + g;
        if (r >= N) return;
        const char* xB = (const char*)x;
        uint roff = ((uint)r << 8) + ((uint)sub << 4);
        float4 xa = *reinterpret_cast<const float4*>(xB + roff);
        float4 xb = *reinterpret_cast<const float4*>(xB + roff + 128);
        float q = xa.x*xa.x + xa.y*xa.y + xa.z*xa.z + xa.w*xa.w
                + xb.x*xb.x + xb.y*xb.y + xb.z*xb.z + xb.w*xb.w;
        q += __shfl_xor(q, 1);
        q += __shfl_xor(q, 2);
        q += __shfl_xor(q, 4);
        float qe  = q + 1e-8f;
        float rnr = rsqrtf(qe);
        if (sub == 0) { rn[r] = rnr; nrm[r] = qe * rnr; }   // nrm = sqrt(qe)
        uint4 p;
        p.x = packbf2(xa.x * rnr, xa.y * rnr);
        p.y = packbf2(xa.z * rnr, xa.w * rnr);
        p.z = packbf2(xb.x * rnr, xb.y * rnr);
        p.w = packbf2(xb.z * rnr, xb.w * rnr);
        xhn[r * 8 + sub] = p;
    } else {
        int e = (blockIdx.x - normBlocks) * blockDim.x + threadIdx.x;
        if (e >= E) return;
        int curr = row[e];
        if (e == 0) {
            for (int r = 0; r <= curr; ++r) row_ptr[r] = 0;
        } else {
            int prev = row[e - 1];
            for (int r = prev + 1; r <= curr; ++r) row_ptr[r] = e;
        }
        if (e == E - 1) {
            for (int r = curr + 1; r <= N; ++r) row_ptr[r] = E;
        }
    }
}

// ---------------------------------------------------------------------------
// Hierarchical counting sort by degree (64 bins) — NO global returned atomics.
// Row placement within a bin is non-deterministic (LDS atomic order), but
// every row's arithmetic and output slot are fixed -> d_out bit-deterministic.
// ---------------------------------------------------------------------------
__global__ void blockhist_kernel(const int* __restrict__ row_ptr,
                                 int* __restrict__ bh, int N) {
    __shared__ int h[64];
    if (threadIdx.x < 64) h[threadIdx.x] = 0;
    __syncthreads();
    int r = blockIdx.x * blockDim.x + threadIdx.x;
    if (r < N) {
        int d = min(row_ptr[r + 1] - row_ptr[r], 63);
        atomicAdd(&h[d], 1);            // LDS, fire-and-forget
    }
    __syncthreads();
    if (threadIdx.x < 64) bh[blockIdx.x * 64 + threadIdx.x] = h[threadIdx.x];
}

__global__ void binscan_kernel(const int* __restrict__ bh,
                               int* __restrict__ boff, int NB) {  // <<<1,64>>>
    int bin = threadIdx.x;
    int total = 0;
    for (int b = 0; b < NB; ++b) total += bh[b * 64 + bin];
    // exclusive scan across bins -> global bin base
    int inc = total;
    #pragma unroll
    for (int off = 1; off < 64; off <<= 1) {
        int t = __shfl_up(inc, off);
        if (bin >= off) inc += t;
    }
    int run = inc - total;
    for (int b = 0; b < NB; ++b) {
        boff[b * 64 + bin] = run;
        run += bh[b * 64 + bin];
    }
}

__global__ void scatter_kernel(const int* __restrict__ row_ptr,
                               const int* __restrict__ boff,
                               int* __restrict__ row_order, int N) {
    __shared__ int fill[64];
    if (threadIdx.x < 64) fill[threadIdx.x] = 0;
    __syncthreads();
    int r = blockIdx.x * blockDim.x + threadIdx.x;
    if (r >= N) return;
    int d = min(row_ptr[r + 1] - row_ptr[r], 63);
    int local = atomicAdd(&fill[d], 1);       // LDS atomic w/ return: on-CU
    row_order[boff[blockIdx.x * 64 + d] + local] = r;
}

// ---------------------------------------------------------------------------
// Kernel 5: FUSED attention + shift-free softmax + aggregation.
// One 8-lane group per DEGREE-SORTED row, 8 rows per wave.  xhn is
// pre-normalized; x_r pre-scaled by beta*rn_r -> att = dot() directly.
// col + nrm are group-uniform scalar loads, 3-stage pipelined.
// ---------------------------------------------------------------------------
__global__ void fused_kernel(const float* __restrict__ x,
                             const uint4* __restrict__ xhn,
                             const float* __restrict__ rn,
                             const float* __restrict__ nrm,
                             const float* __restrict__ beta,
                             const int* __restrict__ row_ptr,
                             const int* __restrict__ col,
                             const int* __restrict__ row_order,
                             float* __restrict__ out, int N, int E) {
    int wid  = blockIdx.x * (blockDim.x >> 6) + (threadIdx.x >> 6);
    int lane = threadIdx.x & 63;
    int g    = lane >> 3;
    int sub  = lane & 7;
    int slot = wid * 8 + g;
    bool rv  = (slot < N);

    int r = 0;
    if (rv) r = row_order[slot];
    int start = 0, deg = 0;
    if (rv) {
        start = row_ptr[r];
        deg   = row_ptr[r + 1] - start;
    }

    // x_r scaled by beta*rn_r:  att = dot(xr_scaled, xhn_c)
    float4 xa = make_float4(0.f, 0.f, 0.f, 0.f);
    float4 xb = make_float4(0.f, 0.f, 0.f, 0.f);
    if (rv) {
        const char* xB = (const char*)x;
        uint roff = ((uint)r << 8) + ((uint)sub << 4);
        xa = *reinterpret_cast<const float4*>(xB + roff);
        xb = *reinterpret_cast<const float4*>(xB + roff + 128);
        float brn = beta[0] * rn[r];
        xa.x *= brn; xa.y *= brn; xa.z *= brn; xa.w *= brn;
        xb.x *= brn; xb.y *= brn; xb.z *= brn; xb.w *= brn;
    }

    int Em1 = E - 1;
    // prologue: cols of quads 0,1; gathers+norms of quad 0 (clamped indices)
    int c0 = col[min(start + 0, Em1)], c1 = col[min(start + 1, Em1)];
    int c2 = col[min(start + 2, Em1)], c3 = col[min(start + 3, Em1)];
    int nc0 = col[min(start + 4, Em1)], nc1 = col[min(start + 5, Em1)];
    int nc2 = col[min(start + 6, Em1)], nc3 = col[min(start + 7, Em1)];
    uint4 q0 = xhn[c0 * 8 + sub], q1 = xhn[c1 * 8 + sub];
    uint4 q2 = xhn[c2 * 8 + sub], q3 = xhn[c3 * 8 + sub];
    float n0 = nrm[c0], n1 = nrm[c1], n2 = nrm[c2], n3 = nrm[c3];

    float  s  = 0.f;
    float4 aa = make_float4(0.f, 0.f, 0.f, 0.f);
    float4 ab = make_float4(0.f, 0.f, 0.f, 0.f);

    for (int base = 0; base < deg; base += 4) {
        // stage A: cols for quad base+8
        int b2 = start + base + 8;
        int t0 = col[min(b2 + 0, Em1)], t1 = col[min(b2 + 1, Em1)];
        int t2 = col[min(b2 + 2, Em1)], t3 = col[min(b2 + 3, Em1)];
        // stage B: gathers + norms for quad base+4
        uint4 nq0 = xhn[nc0 * 8 + sub], nq1 = xhn[nc1 * 8 + sub];
        uint4 nq2 = xhn[nc2 * 8 + sub], nq3 = xhn[nc3 * 8 + sub];
        float nn0 = nrm[nc0], nn1 = nrm[nc1];
        float nn2 = nrm[nc2], nn3 = nrm[nc3];

        // stage C: process current quad
        float4 va0, vb0, va1, vb1, va2, vb2, va3, vb3;
        unpack8(q0, va0, vb0);  unpack8(q1, va1, vb1);
        unpack8(q2, va2, vb2);  unpack8(q3, va3, vb3);

        float d0 = xa.x*va0.x + xa.y*va0.y + xa.z*va0.z + xa.w*va0.w
                 + xb.x*vb0.x + xb.y*vb0.y + xb.z*vb0.z + xb.w*vb0.w;
        float d1 = xa.x*va1.x + xa.y*va1.y + xa.z*va1.z + xa.w*va1.w
                 + xb.x*vb1.x + xb.y*vb1.y + xb.z*vb1.z + xb.w*vb1.w;
        float d2 = xa.x*va2.x + xa.y*va2.y + xa.z*va2.z + xa.w*va2.w
                 + xb.x*vb2.x + xb.y*vb2.y + xb.z*vb2.z + xb.w*vb2.w;
        float d3 = xa.x*va3.x + xa.y*va3.y + xa.z*va3.z + xa.w*va3.w
                 + xb.x*vb3.x + xb.y*vb3.y + xb.z*vb3.z + xb.w*vb3.w;
        d0 += __shfl_xor(d0, 1);  d1 += __shfl_xor(d1, 1);
        d2 += __shfl_xor(d2, 1);  d3 += __shfl_xor(d3, 1);
        d0 += __shfl_xor(d0, 2);  d1 += __shfl_xor(d1, 2);
        d2 += __shfl_xor(d2, 2);  d3 += __shfl_xor(d3, 2);
        d0 += __shfl_xor(d0, 4);  d1 += __shfl_xor(d1, 4);
        d2 += __shfl_xor(d2, 4);  d3 += __shfl_xor(d3, 4);

        float e0 = (base + 0 < deg) ? __expf(d0) : 0.f;  // att bounded by |beta|
        float e1 = (base + 1 < deg) ? __expf(d1) : 0.f;
        float e2 = (base + 2 < deg) ? __expf(d2) : 0.f;
        float e3 = (base + 3 < deg) ? __expf(d3) : 0.f;
        s += (e0 + e1) + (e2 + e3);

        float w0 = e0 * n0, w1 = e1 * n1, w2 = e2 * n2, w3 = e3 * n3;
        aa.x += w0*va0.x + w1*va1.x + w2*va2.x + w3*va3.x;
        aa.y += w0*va0.y + w1*va1.y + w2*va2.y + w3*va3.y;
        aa.z += w0*va0.z + w1*va1.z + w2*va2.z + w3*va3.z;
        aa.w += w0*va0.w + w1*va1.w + w2*va2.w + w3*va3.w;
        ab.x += w0*vb0.x + w1*vb1.x + w2*vb2.x + w3*vb3.x;
        ab.y += w0*vb0.y + w1*vb1.y + w2*vb2.y + w3*vb3.y;
        ab.z += w0*vb0.z + w1*vb1.z + w2*vb2.z + w3*vb3.z;
        ab.w += w0*vb0.w + w1*vb1.w + w2*vb2.w + w3*vb3.w;

        // rotate pipeline
        q0 = nq0; q1 = nq1; q2 = nq2; q3 = nq3;
        n0 = nn0; n1 = nn1; n2 = nn2; n3 = nn3;
        nc0 = t0; nc1 = t1; nc2 = t2; nc3 = t3;
    }

    float inv = 1.0f / fmaxf(s, 1e-16f);      // deg==0 -> out = 0
    if (rv) {
        uint roff = ((uint)r << 8) + ((uint)sub << 4);
        *reinterpret_cast<float4*>((char*)out + roff) =
            make_float4(aa.x * inv, aa.y * inv, aa.z * inv, aa.w * inv);
        *reinterpret_cast<float4*>((char*)out + roff + 128) =
            make_float4(ab.x * inv, ab.y * inv, ab.z * inv, ab.w * inv);
    }
}

// ---------------------------------------------------------------------------
extern "C" void kernel_launch(void* const* d_in, const int* in_sizes, int n_in,
                              void* d_out, int out_size, void* d_ws, size_t ws_size,
                              hipStream_t stream) {
    const float* x    = (const float*)d_in[0];
    const float* beta = (const float*)d_in[1];
    const int*   row  = (const int*)d_in[2];
    const int*   col  = (const int*)d_in[3];
    float*       out  = (float*)d_out;

    const int N  = in_sizes[0] / FEAT;   // 50000
    const int E  = in_sizes[2];          // 800000
    const int NB = (N + 255) / 256;      // histogram blocks

    // Workspace layout (512B-aligned chunks):
    // rn[N] | nrm[N] | row_ptr[N+1] | row_order[N] | bh[NB*64] | boff[NB*64]
    // | xhn[N*8 uint4]
    char*  ws = (char*)d_ws;
    size_t o  = 0;
    auto alloc = [&](size_t bytes) {
        size_t cur = o;
        o = (o + bytes + 511) & ~(size_t)511;
        return cur;
    };
    float* rn        = (float*)(ws + alloc((size_t)N * 4));
    float* nrm       = (float*)(ws + alloc((size_t)N * 4));
    int*   row_ptr   = (int*)  (ws + alloc((size_t)(N + 1) * 4));
    int*   row_order = (int*)  (ws + alloc((size_t)N * 4));
    int*   bh        = (int*)  (ws + alloc((size_t)NB * 64 * 4));
    int*   boff      = (int*)  (ws + alloc((size_t)NB * 64 * 4));
    uint4* xhn       = (uint4*)(ws + alloc((size_t)N * 128));

    {   // prep: norms + normalized bf16 mirror + rowptr
        int normBlocks = (N + 31) / 32;
        int edgeBlocks = (E + 255) / 256;
        prep_kernel<<<normBlocks + edgeBlocks, 256, 0, stream>>>(
            x, rn, nrm, xhn, row, row_ptr, N, E, normBlocks);
    }
    {   // degree counting-sort, hierarchical (no global returned atomics)
        blockhist_kernel<<<NB, 256, 0, stream>>>(row_ptr, bh, N);
        binscan_kernel<<<1, 64, 0, stream>>>(bh, boff, NB);
        scatter_kernel<<<NB, 256, 0, stream>>>(row_ptr, boff, row_order, N);
    }
    {   // fused: 8 degree-sorted rows per wave, 4 waves per block
        int waves = (N + 7) / 8;
        int grid  = (waves + 3) / 4;
        fused_kernel<<<grid, 256, 0, stream>>>(
            x, xhn, rn, nrm, beta, row_ptr, col, row_order, out, N, E);
    }
}

// Round 11
// 43.349 us; speedup vs baseline: 7.0007x; 1.9937x over previous
//
#include <hip/hip_runtime.h>
#include <hip/hip_bf16.h>

#define FEAT 64

// RNE pack of two fp32 into one u32 of 2 bf16 (lo, hi)
__device__ inline uint packbf2(float lo, float hi) {
    uint ul = __float_as_uint(lo), uh = __float_as_uint(hi);
    ul += 0x7FFFu + ((ul >> 16) & 1u);
    uh += 0x7FFFu + ((uh >> 16) & 1u);
    return (ul >> 16) | (uh & 0xFFFF0000u);
}

// unpack uint4 (8 bf16) -> two float4
__device__ inline void unpack8(uint4 q, float4& va, float4& vb) {
    va.x = __uint_as_float(q.x << 16);
    va.y = __uint_as_float(q.x & 0xFFFF0000u);
    va.z = __uint_as_float(q.y << 16);
    va.w = __uint_as_float(q.y & 0xFFFF0000u);
    vb.x = __uint_as_float(q.z << 16);
    vb.y = __uint_as_float(q.z & 0xFFFF0000u);
    vb.z = __uint_as_float(q.w << 16);
    vb.w = __uint_as_float(q.w & 0xFFFF0000u);
}

// ---------------------------------------------------------------------------
// Kernel 1 (merged prep): blocks [0,normBlocks): inverse norms rn, raw norms
// nrm, and the NORMALIZED bf16 mirror xhn = bf16(x * rn) (feature-permuted:
// lane sub holds feats [4s,4s+4) and [32+4s,..) in one uint4).  Remaining
// blocks: row_ptr build from the SORTED row_index.
// ---------------------------------------------------------------------------
__global__ void prep_kernel(const float* __restrict__ x,
                            float* __restrict__ rn,
                            float* __restrict__ nrm,
                            uint4* __restrict__ xhn,
                            const int* __restrict__ row,
                            int* __restrict__ row_ptr,
                            int N, int E, int normBlocks) {
    if ((int)blockIdx.x < normBlocks) {
        int wid  = blockIdx.x * (blockDim.x >> 6) + (threadIdx.x >> 6);
        int lane = threadIdx.x & 63;
        int g    = lane >> 3;
        int sub  = lane & 7;
        int r    = wid * 8 + g;
        if (r >= N) return;
        const char* xB = (const char*)x;
        uint roff = ((uint)r << 8) + ((uint)sub << 4);
        float4 xa = *reinterpret_cast<const float4*>(xB + roff);
        float4 xb = *reinterpret_cast<const float4*>(xB + roff + 128);
        float q = xa.x*xa.x + xa.y*xa.y + xa.z*xa.z + xa.w*xa.w
                + xb.x*xb.x + xb.y*xb.y + xb.z*xb.z + xb.w*xb.w;
        q += __shfl_xor(q, 1);
        q += __shfl_xor(q, 2);
        q += __shfl_xor(q, 4);
        float qe  = q + 1e-8f;
        float rnr = rsqrtf(qe);
        if (sub == 0) { rn[r] = rnr; nrm[r] = qe * rnr; }   // nrm = sqrt(qe)
        uint4 p;
        p.x = packbf2(xa.x * rnr, xa.y * rnr);
        p.y = packbf2(xa.z * rnr, xa.w * rnr);
        p.z = packbf2(xb.x * rnr, xb.y * rnr);
        p.w = packbf2(xb.z * rnr, xb.w * rnr);
        xhn[r * 8 + sub] = p;
    } else {
        int e = (blockIdx.x - normBlocks) * blockDim.x + threadIdx.x;
        if (e >= E) return;
        int curr = row[e];
        if (e == 0) {
            for (int r = 0; r <= curr; ++r) row_ptr[r] = 0;
        } else {
            int prev = row[e - 1];
            for (int r = prev + 1; r <= curr; ++r) row_ptr[r] = e;
        }
        if (e == E - 1) {
            for (int r = curr + 1; r <= N; ++r) row_ptr[r] = E;
        }
    }
}

// ---------------------------------------------------------------------------
// Kernel 2: FUSED attention + shift-free softmax + aggregation.
// ONE WAVE PER ROW, 8 edge-groups of 8 lanes.  deg is wave-uniform: zero
// divergence, no sort needed.  Per 8-edge chunk: 1 coalesced col load,
// 1 nrm gather, 2 width-8 shfls, ONE uint4 gather instruction (8 x 128B
// segments), then per-lane unpack/dot/exp/accumulate.  3-stage pipeline:
// cols for chunk t+2, gather for chunk t+1, process chunk t.
// Cross-group merge: 27 shfl_xor adds (shift-free softmax => plain sums).
// ---------------------------------------------------------------------------
__global__ void fused_kernel(const float* __restrict__ x,
                             const uint4* __restrict__ xhn,
                             const float* __restrict__ rn,
                             const float* __restrict__ nrm,
                             const float* __restrict__ beta,
                             const int* __restrict__ row_ptr,
                             const int* __restrict__ col,
                             float* __restrict__ out, int N) {
    int wv   = threadIdx.x >> 6;
    int r    = blockIdx.x * 4 + wv;
    if (r >= N) return;
    int lane = threadIdx.x & 63;
    int g    = lane >> 3;               // edge-group id (0..7)
    int sub  = lane & 7;                // lane within group
    uint subo = (uint)sub << 4;

    int start = row_ptr[r];
    int deg   = row_ptr[r + 1] - start;

    uint roff = ((uint)r << 8) + subo;
    if (deg == 0) {                     // empty row -> zeros (matches ref)
        *reinterpret_cast<float4*>((char*)out + roff) =
            make_float4(0.f, 0.f, 0.f, 0.f);
        *reinterpret_cast<float4*>((char*)out + roff + 128) =
            make_float4(0.f, 0.f, 0.f, 0.f);
        return;
    }

    // x_r scaled by beta*rn_r (all groups hold the full row slice-wise)
    const char* xB = (const char*)x;
    float4 xa = *reinterpret_cast<const float4*>(xB + roff);
    float4 xb = *reinterpret_cast<const float4*>(xB + roff + 128);
    float brn = beta[0] * rn[r];
    xa.x *= brn; xa.y *= brn; xa.z *= brn; xa.w *= brn;
    xb.x *= brn; xb.y *= brn; xb.z *= brn; xb.w *= brn;

    int last = start + deg - 1;
    int nch  = (deg + 7) >> 3;

    // ---- pipeline prologue ----
    // chunk 0: cols -> shfl -> gather
    int   cc0 = col[min(start + sub, last)];
    float nn0 = nrm[cc0];
    int   c_cur = __shfl(cc0, g, 8);
    float n_cur = __shfl(nn0, g, 8);
    uint4 q_cur = xhn[(uint)c_cur * 8u + sub];
    // chunk 1: cols only
    int   ccA = 0; float nnA = 0.f;
    if (nch > 1) {
        ccA = col[min(start + 8 + sub, last)];
        nnA = nrm[ccA];
    }

    float  s  = 0.f;
    float4 aa = make_float4(0.f, 0.f, 0.f, 0.f);
    float4 ab = make_float4(0.f, 0.f, 0.f, 0.f);

    for (int t = 0; t < nch; ++t) {
        // stage A: cols for chunk t+2 (wave-uniform condition)
        int ccB = 0; float nnB = 0.f;
        if (t + 2 < nch) {
            ccB = col[min(start + (t + 2) * 8 + sub, last)];
            nnB = nrm[ccB];
        }
        // stage B: shfl + gather for chunk t+1
        uint4 q_nxt = q_cur; float n_nxt = n_cur;
        if (t + 1 < nch) {
            int cs = __shfl(ccA, g, 8);
            n_nxt  = __shfl(nnA, g, 8);
            q_nxt  = xhn[(uint)cs * 8u + sub];
        }
        // stage C: process chunk t (edge index = t*8 + g)
        float4 va, vb;
        unpack8(q_cur, va, vb);
        float d = xa.x*va.x + xa.y*va.y + xa.z*va.z + xa.w*va.w
                + xb.x*vb.x + xb.y*vb.y + xb.z*vb.z + xb.w*vb.w;
        d += __shfl_xor(d, 1);
        d += __shfl_xor(d, 2);
        d += __shfl_xor(d, 4);          // group-uniform dot

        bool  valid = (t * 8 + g) < deg;
        float e = valid ? __expf(d) : 0.f;   // att bounded by |beta|
        s += e;
        float w = e * n_cur;            // un-normalize neighbor
        aa.x += w * va.x;  aa.y += w * va.y;
        aa.z += w * va.z;  aa.w += w * va.w;
        ab.x += w * vb.x;  ab.y += w * vb.y;
        ab.z += w * vb.z;  ab.w += w * vb.w;

        // rotate pipeline
        q_cur = q_nxt;  n_cur = n_nxt;
        ccA = ccB;      nnA = nnB;
    }

    // ---- cross-group merge (plain adds: shift-free softmax) ----
    #pragma unroll
    for (int off = 8; off <= 32; off <<= 1) {
        s    += __shfl_xor(s, off);
        aa.x += __shfl_xor(aa.x, off);  aa.y += __shfl_xor(aa.y, off);
        aa.z += __shfl_xor(aa.z, off);  aa.w += __shfl_xor(aa.w, off);
        ab.x += __shfl_xor(ab.x, off);  ab.y += __shfl_xor(ab.y, off);
        ab.z += __shfl_xor(ab.z, off);  ab.w += __shfl_xor(ab.w, off);
    }
    float inv = 1.0f / fmaxf(s, 1e-16f);

    // 16 lanes store the 64 output floats (lane<8: aa slice, else ab slice)
    if (lane < 16) {
        float4 o = (lane < 8) ? aa : ab;
        uint ooff = ((uint)r << 8) + ((uint)lane << 4);
        *reinterpret_cast<float4*>((char*)out + ooff) =
            make_float4(o.x * inv, o.y * inv, o.z * inv, o.w * inv);
    }
}

// ---------------------------------------------------------------------------
extern "C" void kernel_launch(void* const* d_in, const int* in_sizes, int n_in,
                              void* d_out, int out_size, void* d_ws, size_t ws_size,
                              hipStream_t stream) {
    const float* x    = (const float*)d_in[0];
    const float* beta = (const float*)d_in[1];
    const int*   row  = (const int*)d_in[2];
    const int*   col  = (const int*)d_in[3];
    float*       out  = (float*)d_out;

    const int N = in_sizes[0] / FEAT;   // 50000
    const int E = in_sizes[2];          // 800000

    // Workspace layout (512B-aligned chunks):
    // rn[N] | nrm[N] | row_ptr[N+1] | xhn[N*8 uint4]
    char*  ws = (char*)d_ws;
    size_t o  = 0;
    auto alloc = [&](size_t bytes) {
        size_t cur = o;
        o = (o + bytes + 511) & ~(size_t)511;
        return cur;
    };
    float* rn      = (float*)(ws + alloc((size_t)N * 4));
    float* nrm     = (float*)(ws + alloc((size_t)N * 4));
    int*   row_ptr = (int*)  (ws + alloc((size_t)(N + 1) * 4));
    uint4* xhn     = (uint4*)(ws + alloc((size_t)N * 128));

    {   // prep: norms + normalized bf16 mirror + rowptr
        int normBlocks = (N + 31) / 32;
        int edgeBlocks = (E + 255) / 256;
        prep_kernel<<<normBlocks + edgeBlocks, 256, 0, stream>>>(
            x, rn, nrm, xhn, row, row_ptr, N, E, normBlocks);
    }
    {   // fused: 1 wave per row, 4 rows per 256-thread block
        int grid = (N + 3) / 4;
        fused_kernel<<<grid, 256, 0, stream>>>(
            x, xhn, rn, nrm, beta, row_ptr, col, out, N);
    }
}